// Round 5
// baseline (614.079 us; speedup 1.0000x reference)
//
#include <hip/hip_runtime.h>

// AdjointODE: h += dt * ( tanh(h@W1+b1) @ W2 + b2 ), 50 Euler steps.
// BATCH=32768, DIM=128, HID=256.
// ROUND 14: r13 (32 rows/wave, 1 wave/SIMD) + FULL W2 REGISTER CACHE.
// Post-mortems: r11 is LDS-issue-bound (1152 ds_read_b128/CU/step x ~12cyc
// ~= 13.3k cyc measured, LDS ~100% util). r13 halved reads but 1 wave/SIMD
// exposed latencies -> 18.3k cyc (latency wall, MfmaUtil 24). r12's reg
// cache failed ONLY because 512-thr blocks cap archVGPR at 128; r13 proved
// (256,1) allocates freely (144 used, ~512 budget, no-spill to ~450 m08).
// This round: cache ALL 64 W2 frags in registers (256 regs) per wave.
//  - per-wave LDS reads/step: 144 -> 80 (W1 + b1 only)
//  - mm2 weight dep-chain vanishes (register operands)
//  - p-loop FULLY UNROLLED (w2c indices must be compile-time; rule #20)
//  - b2 moved to LDS (saves 32 regs; 8 ds_read_b128/step is noise)
// Live estimate ~420 < 450 no-spill line. Canary: FETCH ~9.3MB, WRITE 16MB,
// dur>=320 or FETCH growth => revert to r11 and declare its LDS roofline.
// Else = r13: two 16-row B-groups/wave, fragment-linear weight LDS,
// h fp32-resident, pk2 packing, b1 as accumulator init (TSCALE-folded).

typedef __attribute__((ext_vector_type(8))) short short8;
typedef __attribute__((ext_vector_type(4))) float float4v;
typedef __attribute__((ext_vector_type(4))) int int4v;

union FB { int4v i; short8 s; };

// LDS map (bytes)
#define W1F_OFF 0        // 64 frags (nt*4+c) x 1 KB = 64 KB
#define W2F_OFF 65536    // 64 frags (p*8+tb) x 1 KB = 64 KB (staging only)
#define B1_OFF  131072   // f32[256] (TSCALE-folded b1)
#define DT_OFF  132096   // f32[64]
#define B2_OFF  132352   // f32[128]
#define LDS_BYTES 132864

#define TSCALE 2.8853900817779268f  // 2/ln2: tanh(x) = 1 - 2/(exp2(x*TSCALE)+1)

__device__ __forceinline__ unsigned rne2(float x) {
  unsigned u = __float_as_uint(x);
  return u + 0x7fffu + ((u >> 16) & 1u);
}

#if __has_builtin(__builtin_amdgcn_cvt_pk_bf16_f32)
__device__ __forceinline__ int pk2(float lo, float hi) {
  return __builtin_bit_cast(int, __builtin_amdgcn_cvt_pk_bf16_f32(lo, hi));
}
#else
__device__ __forceinline__ int pk2(float lo, float hi) {
  return (int)__builtin_amdgcn_perm(rne2(hi), rne2(lo), 0x07060302u);
}
#endif

// B-frag for one 32-K chunk from two C-layout float4 tiles (even, odd).
__device__ __forceinline__ int4v packfrag(float4v e, float4v o) {
  int4v f;
  f.x = pk2(e.x, e.y);
  f.y = pk2(e.z, e.w);
  f.z = pk2(o.x, o.y);
  f.w = pk2(o.z, o.w);
  return f;
}

#define MFMA16(a, b, c) __builtin_amdgcn_mfma_f32_16x16x32_bf16(a, b, c, 0, 0, 0)

extern "C" __global__ __launch_bounds__(256, 1)
void ode_kernel(const float* __restrict__ inp, const float* __restrict__ ts,
                const float* __restrict__ W1, const float* __restrict__ b1,
                const float* __restrict__ W2, const float* __restrict__ b2,
                float* __restrict__ out) {
  __shared__ __align__(16) char ldsb[LDS_BYTES];
  float* b1f = (float*)(ldsb + B1_OFF);
  float* dtf = (float*)(ldsb + DT_OFF);
  float* b2f = (float*)(ldsb + B2_OFF);

  const int tid = threadIdx.x;
  const int lane = tid & 63, wave = tid >> 6;
  const int ln = lane & 15;  // batch-row within group
  const int q = lane >> 4;   // quad
  const int rowa = blockIdx.x * 128 + wave * 32 + ln;  // group A row
  const int rowb = rowa + 16;                          // group B row

  // ---- stage W1 frags: pi = (fid=nt*4+c)*64 + L; 256 thr x 16 iters ----
  #pragma unroll 1
  for (int it = 0; it < 16; it++) {
    const int pi = it * 256 + tid;  // [0, 4096)
    const int fid = pi >> 6, L = pi & 63;
    const int nt = fid >> 2, c = fid & 3;
    const int lf = L & 15, qf = L >> 4;
    const int n = nt * 16 + lf;            // hid index (A-frag m-row)
    const int kb = c * 32 + qf * 4;        // logical dim base
    float v0 = W1[(kb + 0) * 256 + n] * TSCALE;
    float v1 = W1[(kb + 1) * 256 + n] * TSCALE;
    float v2 = W1[(kb + 2) * 256 + n] * TSCALE;
    float v3 = W1[(kb + 3) * 256 + n] * TSCALE;
    float v4 = W1[(kb + 16) * 256 + n] * TSCALE;
    float v5 = W1[(kb + 17) * 256 + n] * TSCALE;
    float v6 = W1[(kb + 18) * 256 + n] * TSCALE;
    float v7 = W1[(kb + 19) * 256 + n] * TSCALE;
    int4v d = {pk2(v0, v1), pk2(v2, v3), pk2(v4, v5), pk2(v6, v7)};
    *(int4v*)(ldsb + W1F_OFF + pi * 16) = d;
  }
  // ---- stage W2 frags: fid = p*8 + tb (staging for the register cache) ----
  #pragma unroll 1
  for (int it = 0; it < 16; it++) {
    const int pi = it * 256 + tid;
    const int fid = pi >> 6, L = pi & 63;
    const int p = fid >> 3, tb = fid & 7;
    const int lf = L & 15, qf = L >> 4;
    const int d_out = tb * 16 + lf;        // output-dim (A-frag m-row)
    const int kb = p * 32 + qf * 4;        // logical hid base
    float v0 = W2[(kb + 0) * 128 + d_out];
    float v1 = W2[(kb + 1) * 128 + d_out];
    float v2 = W2[(kb + 2) * 128 + d_out];
    float v3 = W2[(kb + 3) * 128 + d_out];
    float v4 = W2[(kb + 16) * 128 + d_out];
    float v5 = W2[(kb + 17) * 128 + d_out];
    float v6 = W2[(kb + 18) * 128 + d_out];
    float v7 = W2[(kb + 19) * 128 + d_out];
    int4v d = {pk2(v0, v1), pk2(v2, v3), pk2(v4, v5), pk2(v6, v7)};
    *(int4v*)(ldsb + W2F_OFF + pi * 16) = d;
  }
  b1f[tid] = b1[tid] * TSCALE;       // 256 threads == 256 entries
  if (tid < 128) b2f[tid] = b2[tid];
  if (tid < 50) dtf[tid] = ts[tid + 1] - ts[tid];

  // ---- load h for both groups ----
  float4v h4a[8], h4b[8];
  #pragma unroll
  for (int tb = 0; tb < 8; tb++) {
    h4a[tb] = *(const float4v*)&inp[rowa * 128 + tb * 16 + q * 4];
    h4b[tb] = *(const float4v*)&inp[rowb * 128 + tb * 16 + q * 4];
  }

  __syncthreads();  // the only barrier

  // per-lane frag base pointers
  const int4v* w1f = (const int4v*)(ldsb + W1F_OFF) + lane;
  const int4v* w2f = (const int4v*)(ldsb + W2F_OFF) + lane;

  // ---- register-cache ALL of W2: 64 frags x 4 regs = 256 regs ----
  // (static indices everywhere; loaded once, reused 50 steps)
  FB w2c[64];
  #pragma unroll
  for (int i = 0; i < 64; i++)
    w2c[i].i = w2f[i * 64];

  #pragma unroll 1
  for (int s = 0; s < 50; s++) {
    const float dt = dtf[s];
    const float m2dt = -2.0f * dt;

    // ---- states -> B-frags (pure register packing) ----
    FB hba[4], hbb[4];
    #pragma unroll
    for (int kc = 0; kc < 4; kc++) {
      hba[kc].i = packfrag(h4a[2 * kc], h4a[2 * kc + 1]);
      hbb[kc].i = packfrag(h4b[2 * kc], h4b[2 * kc + 1]);
    }

    // ---- rotated depth-1 pipeline, FULLY UNROLLED over p ----
    // per p: mm1(p); mm2(p-1) from w2c (static); act(p)
    FB afa, afb;
    #pragma unroll
    for (int p = 0; p < 8; p++) {
      const int nt0 = 2 * p, nt1 = 2 * p + 1;
      FB wA[4], wB[4];
      #pragma unroll
      for (int c = 0; c < 4; c++) {
        wA[c].i = w1f[(nt0 * 4 + c) * 64];
        wB[c].i = w1f[(nt1 * 4 + c) * 64];
      }
      const float4v bi0 = *(const float4v*)&b1f[nt0 * 16 + q * 4];
      const float4v bi1 = *(const float4v*)&b1f[nt1 * 16 + q * 4];
      float4v g0a = bi0, g1a = bi1, g0b = bi0, g1b = bi1;
      #pragma unroll
      for (int c = 0; c < 4; c++) {
        g0a = MFMA16(wA[c].s, hba[c].s, g0a);
        g1a = MFMA16(wB[c].s, hba[c].s, g1a);
        g0b = MFMA16(wA[c].s, hbb[c].s, g0b);
        g1b = MFMA16(wB[c].s, hbb[c].s, g1b);
      }
      // mm2(p-1): consumes afa/afb from previous chunk, weights from regs
      if (p >= 1) {
        #pragma unroll
        for (int tb = 0; tb < 8; tb++) {
          h4a[tb] = MFMA16(w2c[(p - 1) * 8 + tb].s, afa.s, h4a[tb]);
          h4b[tb] = MFMA16(w2c[(p - 1) * 8 + tb].s, afb.s, h4b[tb]);
        }
      }
      // act(p): refill afa/afb (trans chain drains under next chunk's MFMAs)
      float4v a0a, a1a, a0b, a1b;
      #pragma unroll
      for (int r = 0; r < 4; r++) {
        a0a[r] = fmaf(__builtin_amdgcn_rcpf(__builtin_amdgcn_exp2f(g0a[r]) + 1.0f), m2dt, dt);
        a1a[r] = fmaf(__builtin_amdgcn_rcpf(__builtin_amdgcn_exp2f(g1a[r]) + 1.0f), m2dt, dt);
        a0b[r] = fmaf(__builtin_amdgcn_rcpf(__builtin_amdgcn_exp2f(g0b[r]) + 1.0f), m2dt, dt);
        a1b[r] = fmaf(__builtin_amdgcn_rcpf(__builtin_amdgcn_exp2f(g1b[r]) + 1.0f), m2dt, dt);
      }
      afa.i = packfrag(a0a, a1a);
      afb.i = packfrag(a0b, a1b);
    }

    // epilogue: mm2(7) from regs
    #pragma unroll
    for (int tb = 0; tb < 8; tb++) {
      h4a[tb] = MFMA16(w2c[56 + tb].s, afa.s, h4a[tb]);
      h4b[tb] = MFMA16(w2c[56 + tb].s, afb.s, h4b[tb]);
    }

    // ---- h += dt * b2 (b2 from LDS; saves 32 resident regs) ----
    #pragma unroll
    for (int tb = 0; tb < 8; tb++) {
      const float4v bv = *(const float4v*)&b2f[tb * 16 + q * 4];
      #pragma unroll
      for (int r = 0; r < 4; r++) {
        h4a[tb][r] = fmaf(dt, bv[r], h4a[tb][r]);
        h4b[tb][r] = fmaf(dt, bv[r], h4b[tb][r]);
      }
    }
  }

  // ---- store both groups ----
  #pragma unroll
  for (int tb = 0; tb < 8; tb++) {
    *(float4v*)&out[rowa * 128 + tb * 16 + q * 4] = h4a[tb];
    *(float4v*)&out[rowb * 128 + tb * 16 + q * 4] = h4b[tb];
  }
}

extern "C" void kernel_launch(void* const* d_in, const int* in_sizes, int n_in,
                              void* d_out, int out_size, void* d_ws, size_t ws_size,
                              hipStream_t stream) {
  const float* inp = (const float*)d_in[0];
  const float* ts  = (const float*)d_in[1];
  const float* W1  = (const float*)d_in[2];
  const float* b1  = (const float*)d_in[3];
  const float* W2  = (const float*)d_in[4];
  const float* b2  = (const float*)d_in[5];
  hipLaunchKernelGGL(ode_kernel, dim3(256), dim3(256), 0, stream,
                     inp, ts, W1, b1, W2, b2, (float*)d_out);
}